// Round 1
// baseline (120676.208 us; speedup 1.0000x reference)
//
#include <hip/hip_runtime.h>
#include <hip/hip_cooperative_groups.h>
#include <math.h>

namespace cg = cooperative_groups;

// Problem constants
constexpr int kB = 64, kS = 24, kT = 96, kE = 256, kH = 512, kA = 512;
constexpr int NWG = 256, NTH = 256;

__device__ __forceinline__ float sigmoidf(float x) { return 1.0f / (1.0f + expf(-x)); }
__device__ __forceinline__ float dot4(float4 a, float4 b) {
  return a.x * b.x + a.y * b.y + a.z * b.z + a.w * b.w;
}

// One cooperative kernel does the whole pipeline.
// WG g owns h-columns {2g, 2g+1}  -> gate columns {q*512 + 2g + p : q=0..3, p=0..1}
// Word/sentence cell state c for owned columns lives in LDS (never leaves the WG).
// Global h is double-buffered in ws; one grid.sync per recurrent step.
__global__ __launch_bounds__(NTH) void ha_kernel(
    const int* __restrict__ captions, const int* __restrict__ masks,
    const float* __restrict__ embed_W,
    const float* __restrict__ w_Wih, const float* __restrict__ w_Whh,
    const float* __restrict__ w_bih, const float* __restrict__ w_bhh,
    const float* __restrict__ s_Wih, const float* __restrict__ s_Whh,
    const float* __restrict__ s_bih, const float* __restrict__ s_bhh,
    const float* __restrict__ wa_Wk, const float* __restrict__ wa_Wv,
    const float* __restrict__ sa_Wk, const float* __restrict__ sa_Wv,
    float* __restrict__ out, float* __restrict__ ws) {
  cg::grid_group grid = cg::this_grid();
  const int g = blockIdx.x;
  const int tid = threadIdx.x;

  // ws layout (floats): total ~4.10M floats = 16.4 MB
  float* h_buf = ws;                     // 2 * kB*kH   (double-buffered word h)
  float* sh_buf = h_buf + 2 * kB * kH;   // 2 * kB*kH   (double-buffered sentence h)
  float* hs_buf = sh_buf + 2 * kB * kH;  // kB*kT*kH    (current sentence word_hs)
  float* z_buf = hs_buf + kB * kT * kH;  // kB*kT
  float* ctx_ws = z_buf + kB * kT;       // kB*kH
  float* sent_hs = ctx_ws + kB * kH;     // kB*kS*kH
  float* z2_buf = sent_hs + kB * kS * kH;  // kB*kS

  // LDS (~53 KB). +4 float padding on weight rows: row stride mod 32 = 4
  // -> 8 distinct jj rows map to distinct bank groups (no 8-way conflict).
  __shared__ __align__(16) float wih_s[8][kE + 4];
  __shared__ __align__(16) float whh_s[8][kH + 4];
  __shared__ float bias_s[8];
  __shared__ float g_s[8][kB + 2];
  __shared__ float c_s[2][kB];
  __shared__ float hown_s[2][kB];
  __shared__ float sc_s[2][kB];
  __shared__ __align__(16) float attn_s[12][kH];
  __shared__ float soft_s[kT];
  __shared__ float red_s[4 * 12];

  // ---- init: load word-LSTM weight slice into LDS, zero states ----
  for (int idx = tid; idx < 8 * kE; idx += NTH) {
    int jj = idx >> 8, e = idx & (kE - 1);
    int row = (jj >> 1) * kH + 2 * g + (jj & 1);
    wih_s[jj][e] = w_Wih[row * kE + e];
  }
  for (int idx = tid; idx < 8 * kH; idx += NTH) {
    int jj = idx >> 9, k = idx & (kH - 1);
    int row = (jj >> 1) * kH + 2 * g + (jj & 1);
    whh_s[jj][k] = w_Whh[row * kH + k];
  }
  if (tid < 8) {
    int row = (tid >> 1) * kH + 2 * g + (tid & 1);
    bias_s[tid] = w_bih[row] + w_bhh[row];
  }
  if (tid < kB) {
    c_s[0][tid] = 0.f; c_s[1][tid] = 0.f;
    hown_s[0][tid] = 0.f; hown_s[1][tid] = 0.f;
    sc_s[0][tid] = 0.f; sc_s[1][tid] = 0.f;
  }
  {
    int idx = g * NTH + tid;  // 65536 threads == 2*kB*kH exactly
    h_buf[idx] = 0.0f;
    sh_buf[idx] = 0.0f;
  }
  grid.sync();

  int gstep = 0;
  for (int s = 0; s < kS; ++s) {
    // ================= word LSTM: 96 steps =================
    for (int t = 0; t < kT; ++t, ++gstep) {
      const float* hcur = h_buf + (gstep & 1) * kB * kH;
      float* hnxt = h_buf + ((gstep + 1) & 1) * kB * kH;
      const int jj = tid & 7, bb = tid >> 3;  // bb in 0..31; handles b=bb and b=bb+32
      float acc0 = bias_s[jj], acc1 = acc0;
      const int cap0 = captions[(bb * kS + s) * kT + t];
      const int cap1 = captions[((bb + 32) * kS + s) * kT + t];
      const float4* __restrict__ x0 = (const float4*)(embed_W + (size_t)cap0 * kE);
      const float4* __restrict__ x1 = (const float4*)(embed_W + (size_t)cap1 * kE);
      const float4* wi = (const float4*)(&wih_s[jj][0]);
#pragma unroll 4
      for (int e = 0; e < kE / 4; ++e) {
        float4 w = wi[e];
        acc0 += dot4(w, x0[e]);
        acc1 += dot4(w, x1[e]);
      }
      const float4* __restrict__ h0 = (const float4*)(hcur + bb * kH);
      const float4* __restrict__ h1 = (const float4*)(hcur + (bb + 32) * kH);
      const float4* wh = (const float4*)(&whh_s[jj][0]);
#pragma unroll 4
      for (int k = 0; k < kH / 4; ++k) {
        float4 w = wh[k];
        acc0 += dot4(w, h0[k]);
        acc1 += dot4(w, h1[k]);
      }
      g_s[jj][bb] = acc0;
      g_s[jj][bb + 32] = acc1;
      __syncthreads();
      if (tid < 128) {
        const int p = tid & 1, b = tid >> 1;
        float gi = g_s[0 + p][b], gf = g_s[2 + p][b], gg = g_s[4 + p][b], go = g_s[6 + p][b];
        float cold = c_s[p][b];
        float c2 = sigmoidf(gf) * cold + sigmoidf(gi) * tanhf(gg);
        float h2 = sigmoidf(go) * tanhf(c2);
        const int m = masks[(b * kS + s) * kT + t];
        float cn = m ? c2 : cold;
        float hn = m ? h2 : hown_s[p][b];
        c_s[p][b] = cn;
        hown_s[p][b] = hn;
        const int col = 2 * g + p;
        hnxt[b * kH + col] = hn;
        hs_buf[(b * kT + t) * kH + col] = m ? h2 : 0.0f;
      }
      grid.sync();
    }

    // ================= word attention: z[b,t] =================
    // WG g handles b = g>>2, t in [(g&3)*24, +24), split in two halves of 12.
    {
      const int ab = g >> 2;
      const int at0 = (g & 3) * 24;
      for (int half = 0; half < 2; ++half) {
        const int tb = at0 + half * 12;
        for (int idx = tid; idx < 12 * kH; idx += NTH) {
          int pp = idx >> 9, hh = idx & (kH - 1);
          attn_s[pp][hh] = hs_buf[(ab * kT + tb + pp) * kH + hh];
        }
        __syncthreads();
        float part[12];
#pragma unroll
        for (int p = 0; p < 12; ++p) part[p] = 0.0f;
        for (int a0 = 0; a0 < kA; a0 += NTH) {
          const int aa = a0 + tid;
          float dacc[12];
#pragma unroll
          for (int p = 0; p < 12; ++p) dacc[p] = 0.0f;
          const float4* wk = (const float4*)(wa_Wk + aa * kH);
          for (int k = 0; k < kH / 4; ++k) {
            float4 w = wk[k];
#pragma unroll
            for (int p = 0; p < 12; ++p)
              dacc[p] += dot4(w, *(const float4*)(&attn_s[p][k * 4]));
          }
          const float wv = wa_Wv[aa];
#pragma unroll
          for (int p = 0; p < 12; ++p) part[p] += wv * tanhf(dacc[p]);
        }
        const int lane = tid & 63, wid = tid >> 6;
#pragma unroll
        for (int p = 0; p < 12; ++p) {
          float v = part[p];
          v += __shfl_down(v, 32); v += __shfl_down(v, 16); v += __shfl_down(v, 8);
          v += __shfl_down(v, 4);  v += __shfl_down(v, 2);  v += __shfl_down(v, 1);
          if (lane == 0) red_s[wid * 12 + p] = v;
        }
        __syncthreads();
        if (tid < 12)
          z_buf[ab * kT + tb + tid] =
              red_s[tid] + red_s[12 + tid] + red_s[24 + tid] + red_s[36 + tid];
        __syncthreads();
      }
    }
    grid.sync();

    // ================= softmax over T + ctx =================
    if (g < kB) {
      const int b = g;
      if (tid < kT) soft_s[tid] = z_buf[b * kT + tid];
      __syncthreads();
      float mx = -1e30f;
      for (int i = 0; i < kT; ++i) mx = fmaxf(mx, soft_s[i]);
      float den = 0.0f;
      for (int i = 0; i < kT; ++i) den += expf(soft_s[i] - mx);
      __syncthreads();
      if (tid < kT) soft_s[tid] = expf(soft_s[tid] - mx) / den;
      __syncthreads();
      for (int h0 = tid; h0 < kH; h0 += NTH) {
        float acc = 0.0f;
        for (int tt = 0; tt < kT; ++tt) acc += soft_s[tt] * hs_buf[(b * kT + tt) * kH + h0];
        ctx_ws[b * kH + h0] = acc;
      }
    }
    grid.sync();

    // ================= sentence LSTM step =================
    {
      const float* shc = sh_buf + (s & 1) * kB * kH;
      float* shn = sh_buf + ((s + 1) & 1) * kB * kH;
      const int jj = tid & 7, bb = tid >> 3;
      const int row = (jj >> 1) * kH + 2 * g + (jj & 1);
      float acc0 = s_bih[row] + s_bhh[row];
      float acc1 = acc0;
      const float4* wi = (const float4*)(s_Wih + row * kH);
      const float4* wh = (const float4*)(s_Whh + row * kH);
      const float4* x0 = (const float4*)(ctx_ws + bb * kH);
      const float4* x1 = (const float4*)(ctx_ws + (bb + 32) * kH);
      const float4* h0 = (const float4*)(shc + bb * kH);
      const float4* h1 = (const float4*)(shc + (bb + 32) * kH);
#pragma unroll 2
      for (int k = 0; k < kH / 4; ++k) {
        float4 a = wi[k], c = wh[k];
        acc0 += dot4(a, x0[k]) + dot4(c, h0[k]);
        acc1 += dot4(a, x1[k]) + dot4(c, h1[k]);
      }
      g_s[jj][bb] = acc0;
      g_s[jj][bb + 32] = acc1;
      __syncthreads();
      if (tid < 128) {
        const int p = tid & 1, b = tid >> 1;
        float gi = g_s[0 + p][b], gf = g_s[2 + p][b], gg = g_s[4 + p][b], go = g_s[6 + p][b];
        float c2 = sigmoidf(gf) * sc_s[p][b] + sigmoidf(gi) * tanhf(gg);
        float h2 = sigmoidf(go) * tanhf(c2);
        sc_s[p][b] = c2;
        const int col = 2 * g + p;
        shn[b * kH + col] = h2;
        sent_hs[(b * kS + s) * kH + col] = h2;
      }
    }
    grid.sync();
  }

  // ================= final attention over S =================
  {
    const int pair0 = g * 6;  // 1536 (b,s) pairs / 256 WGs
    for (int idx = tid; idx < 6 * kH; idx += NTH) {
      int pp = idx >> 9, hh = idx & (kH - 1);
      attn_s[pp][hh] = sent_hs[(pair0 + pp) * kH + hh];
    }
    __syncthreads();
    float part[6];
#pragma unroll
    for (int p = 0; p < 6; ++p) part[p] = 0.0f;
    for (int a0 = 0; a0 < kA; a0 += NTH) {
      const int aa = a0 + tid;
      float dacc[6];
#pragma unroll
      for (int p = 0; p < 6; ++p) dacc[p] = 0.0f;
      const float4* wk = (const float4*)(sa_Wk + aa * kH);
      for (int k = 0; k < kH / 4; ++k) {
        float4 w = wk[k];
#pragma unroll
        for (int p = 0; p < 6; ++p)
          dacc[p] += dot4(w, *(const float4*)(&attn_s[p][k * 4]));
      }
      const float wv = sa_Wv[aa];
#pragma unroll
      for (int p = 0; p < 6; ++p) part[p] += wv * tanhf(dacc[p]);
    }
    const int lane = tid & 63, wid = tid >> 6;
#pragma unroll
    for (int p = 0; p < 6; ++p) {
      float v = part[p];
      v += __shfl_down(v, 32); v += __shfl_down(v, 16); v += __shfl_down(v, 8);
      v += __shfl_down(v, 4);  v += __shfl_down(v, 2);  v += __shfl_down(v, 1);
      if (lane == 0) red_s[wid * 6 + p] = v;
    }
    __syncthreads();
    if (tid < 6)
      z2_buf[pair0 + tid] = red_s[tid] + red_s[6 + tid] + red_s[12 + tid] + red_s[18 + tid];
  }
  grid.sync();

  if (g < kB) {
    const int b = g;
    if (tid < kS) soft_s[tid] = z2_buf[b * kS + tid];
    __syncthreads();
    float mx = -1e30f;
    for (int i = 0; i < kS; ++i) mx = fmaxf(mx, soft_s[i]);
    float den = 0.0f;
    for (int i = 0; i < kS; ++i) den += expf(soft_s[i] - mx);
    __syncthreads();
    if (tid < kS) {
      float al = expf(soft_s[tid] - mx) / den;
      soft_s[tid] = al;
      out[kB * kH + b * kS + tid] = al;  // alpha output
    }
    __syncthreads();
    for (int h0 = tid; h0 < kH; h0 += NTH) {
      float acc = 0.0f;
      for (int s2 = 0; s2 < kS; ++s2) acc += soft_s[s2] * sent_hs[(b * kS + s2) * kH + h0];
      out[b * kH + h0] = acc;  // context output
    }
  }
}

extern "C" void kernel_launch(void* const* d_in, const int* in_sizes, int n_in,
                              void* d_out, int out_size, void* d_ws, size_t ws_size,
                              hipStream_t stream) {
  (void)in_sizes; (void)n_in; (void)out_size; (void)ws_size;
  const int* captions = (const int*)d_in[0];
  const int* masks = (const int*)d_in[1];
  const float* embed_W = (const float*)d_in[2];
  const float* w_Wih = (const float*)d_in[3];
  const float* w_Whh = (const float*)d_in[4];
  const float* w_bih = (const float*)d_in[5];
  const float* w_bhh = (const float*)d_in[6];
  const float* s_Wih = (const float*)d_in[7];
  const float* s_Whh = (const float*)d_in[8];
  const float* s_bih = (const float*)d_in[9];
  const float* s_bhh = (const float*)d_in[10];
  const float* wa_Wk = (const float*)d_in[11];
  const float* wa_Wv = (const float*)d_in[12];
  const float* sa_Wk = (const float*)d_in[13];
  const float* sa_Wv = (const float*)d_in[14];
  float* out = (float*)d_out;
  float* ws = (float*)d_ws;

  void* args[] = {&captions, &masks, &embed_W, &w_Wih, &w_Whh, &w_bih, &w_bhh,
                  &s_Wih, &s_Whh, &s_bih, &s_bhh, &wa_Wk, &wa_Wv, &sa_Wk, &sa_Wv,
                  &out, &ws};
  hipLaunchCooperativeKernel((void*)ha_kernel, dim3(NWG), dim3(NTH), args, 0, stream);
}

// Round 2
// 48542.310 us; speedup vs baseline: 2.4860x; 2.4860x over previous
//
#include <hip/hip_runtime.h>
#include <hip/hip_cooperative_groups.h>
#include <math.h>

namespace cg = cooperative_groups;

constexpr int kB = 64, kS = 24, kT = 96, kE = 256, kH = 512, kA = 512;
constexpr int NWG = 256, NTH = 512;

// ws layout (floats)
constexpr int OFF_H   = 0;                         // 2*kB*kH double-buffered word h
constexpr int OFF_SH  = OFF_H + 2 * kB * kH;       // 2*kB*kH double-buffered sent h
constexpr int OFF_HS  = OFF_SH + 2 * kB * kH;      // kB*kT*kH word_hs (current sentence)
constexpr int OFF_Z   = OFF_HS + kB * kT * kH;     // kB*kT
constexpr int OFF_CTX = OFF_Z + kB * kT;           // kB*kH
constexpr int OFF_SHS = OFF_CTX + kB * kH;         // kB*kS*kH
constexpr int OFF_Z2  = OFF_SHS + kB * kS * kH;    // kB*kS
constexpr int OFF_BAR = (OFF_Z2 + kB * kS + 31) & ~31;  // 17 counters, 128B apart

__device__ __forceinline__ float sigmoidf(float x) { return 1.0f / (1.0f + expf(-x)); }
__device__ __forceinline__ float dot4(float4 a, float4 b) {
  return a.x * b.x + a.y * b.y + a.z * b.z + a.w * b.w;
}

// Two-level split-phase grid barrier. Monotonic counters (no reset).
// group = g & 15 (16 groups x 16 WGs). All WGs must call every barrier.
__device__ __forceinline__ void bar_arrive(unsigned* grpc, unsigned* rootc,
                                           int nbar, int g, int tid) {
  __syncthreads();  // all WG work (incl. global writes) done before arrive
  if (tid == 0) {
    unsigned old = __hip_atomic_fetch_add(&grpc[(g & 15) * 32], 1u,
                                          __ATOMIC_RELEASE, __HIP_MEMORY_SCOPE_AGENT);
    if (old == (unsigned)(16 * nbar - 1))
      __hip_atomic_fetch_add(rootc, 1u, __ATOMIC_RELEASE, __HIP_MEMORY_SCOPE_AGENT);
  }
}
__device__ __forceinline__ void bar_wait(unsigned* rootc, int nbar, int tid) {
  if (tid == 0) {
    while (__hip_atomic_load(rootc, __ATOMIC_ACQUIRE, __HIP_MEMORY_SCOPE_AGENT) <
           (unsigned)(16 * nbar))
      __builtin_amdgcn_s_sleep(1);
  }
  __syncthreads();
}

__global__ __launch_bounds__(NTH) void ha_kernel(
    const int* __restrict__ captions, const int* __restrict__ masks,
    const float* __restrict__ embed_W,
    const float* __restrict__ w_Wih, const float* __restrict__ w_Whh,
    const float* __restrict__ w_bih, const float* __restrict__ w_bhh,
    const float* __restrict__ s_Wih, const float* __restrict__ s_Whh,
    const float* __restrict__ s_bih, const float* __restrict__ s_bhh,
    const float* __restrict__ wa_Wk, const float* __restrict__ wa_Wv,
    const float* __restrict__ sa_Wk, const float* __restrict__ sa_Wv,
    float* __restrict__ out, float* __restrict__ ws) {
  cg::grid_group grid = cg::this_grid();
  const int g = blockIdx.x, tid = threadIdx.x;
  const int jj = tid & 7, bb = tid >> 3;  // jj: K-slice / gate-col index, bb: batch

  float* h_buf = ws + OFF_H;
  float* sh_buf = ws + OFF_SH;
  float* hs_buf = ws + OFF_HS;
  float* z_buf = ws + OFF_Z;
  float* ctx_ws = ws + OFF_CTX;
  float* sent_hs = ws + OFF_SHS;
  float* z2_buf = ws + OFF_Z2;
  unsigned* grpc = (unsigned*)(ws + OFF_BAR);
  unsigned* rootc = grpc + 16 * 32;

  // LDS: ~60.6 KB static. Row pads keep 16B alignment (260*4, 516*4 are /16).
  __shared__ __align__(16) float wih_s[8][260];
  __shared__ __align__(16) float whh_s[8][516];
  __shared__ float bias_s[8];
  __shared__ __align__(16) float smem_u[8192];  // hpart+xpart, aliased as attn
  __shared__ float g_s[8][66];
  __shared__ float c_s[2][kB], hown_s[2][kB], sc_s[2][kB];
  __shared__ float soft_s[kT], red_s[96];

  // hpart[c][bb][jj]: write addr = (c*512 + bb*8 + jj)*4 -> banks (8bb+jj)%32:
  // 2-way aliasing only (free per m136).
  float (*hpart)[kB][8] = reinterpret_cast<float (*)[kB][8]>(&smem_u[0]);
  float (*xpart)[kB][8] = reinterpret_cast<float (*)[kB][8]>(&smem_u[4096]);
  float* attn_f = &smem_u[0];  // attention phases: 12 rows x 516 stride

  // ---- init ----
  for (int idx = tid; idx < 8 * kE; idx += NTH) {
    int c = idx >> 8, e = idx & (kE - 1);
    wih_s[c][e] = w_Wih[((c >> 1) * kH + 2 * g + (c & 1)) * kE + e];
  }
  for (int idx = tid; idx < 8 * kH; idx += NTH) {
    int c = idx >> 9, k = idx & (kH - 1);
    whh_s[c][k] = w_Whh[((c >> 1) * kH + 2 * g + (c & 1)) * kH + k];
  }
  if (tid < 8) {
    int row = (tid >> 1) * kH + 2 * g + (tid & 1);
    bias_s[tid] = w_bih[row] + w_bhh[row];
  }
  if (tid < kB) {
    c_s[0][tid] = 0.f; c_s[1][tid] = 0.f;
    hown_s[0][tid] = 0.f; hown_s[1][tid] = 0.f;
    sc_s[0][tid] = 0.f; sc_s[1][tid] = 0.f;
  }
  {
    int idx = g * NTH + tid;  // 131072 == 2*(2*kB*kH): zero both h buffers
    if (idx < 2 * kB * kH) h_buf[idx] = 0.f;
    else sh_buf[idx - 2 * kB * kH] = 0.f;
  }
  if (g == 0)
    for (int idx = tid; idx < 17 * 32; idx += NTH) grpc[idx] = 0u;
  grid.sync();  // publish zeroed barrier counters + h buffers

  // xg prefetch: K-split x@Wih^T partials for own 8 gate cols -> xpart
  auto prefetch = [&](int s2, int t2) {
    const int cap = captions[(bb * kS + s2) * kT + t2];
    const float4* __restrict__ xrow = (const float4*)(embed_W + (size_t)cap * kE);
    float xacc[8];
#pragma unroll
    for (int c = 0; c < 8; ++c) xacc[c] = 0.f;
#pragma unroll 2
    for (int i = 0; i < 8; ++i) {
      const int ch = jj + (i << 3);
      float4 xv = xrow[ch];
#pragma unroll
      for (int c = 0; c < 8; ++c)
        xacc[c] += dot4(*(const float4*)(&wih_s[c][ch << 2]), xv);
    }
#pragma unroll
    for (int c = 0; c < 8; ++c) xpart[c][bb][jj] = xacc[c];
  };

  int nbar = 0, gstep = 0;
  for (int s = 0; s < kS; ++s) {
    prefetch(s, 0);  // consumed after (A)'s __syncthreads at t=0

    // ================= word LSTM: 96 steps =================
    for (int t = 0; t < kT; ++t, ++gstep) {
      const float* hcur = h_buf + (gstep & 1) * kB * kH;
      float* hnxt = h_buf + ((gstep + 1) & 1) * kB * kH;

      // (A) h-part partial dots: thread (jj,bb) covers k-chunks {jj+8i}
      {
        const float4* __restrict__ hrow = (const float4*)(hcur + bb * kH);
        float acc[8];
#pragma unroll
        for (int c = 0; c < 8; ++c) acc[c] = 0.f;
#pragma unroll 4
        for (int i = 0; i < 16; ++i) {
          const int ch = jj + (i << 3);
          float4 hv = hrow[ch];
#pragma unroll
          for (int c = 0; c < 8; ++c)
            acc[c] += dot4(*(const float4*)(&whh_s[c][ch << 2]), hv);
        }
#pragma unroll
        for (int c = 0; c < 8; ++c) hpart[c][bb][jj] = acc[c];
      }
      __syncthreads();

      // (B) assemble gates (h-part + prefetched x-part), nonlinearity, state update
      if (tid < 128) {
        const int p = tid & 1, b = tid >> 1;
        float gate[4];
#pragma unroll
        for (int q = 0; q < 4; ++q) {
          const int c = (q << 1) | p;
          float sum = bias_s[c];
#pragma unroll
          for (int j = 0; j < 8; ++j) sum += hpart[c][b][j] + xpart[c][b][j];
          gate[q] = sum;
        }
        float cold = c_s[p][b];
        float c2 = sigmoidf(gate[1]) * cold + sigmoidf(gate[0]) * tanhf(gate[2]);
        float h2 = sigmoidf(gate[3]) * tanhf(c2);
        const int m = masks[(b * kS + s) * kT + t];
        float cn = m ? c2 : cold;
        float hn = m ? h2 : hown_s[p][b];
        c_s[p][b] = cn;
        hown_s[p][b] = hn;
        const int col = 2 * g + p;
        hnxt[b * kH + col] = hn;
        hs_buf[(b * kT + t) * kH + col] = m ? h2 : 0.f;
      }

      ++nbar;
      bar_arrive(grpc, rootc, nbar, g, tid);
      if (t < kT - 1) prefetch(s, t + 1);  // hidden in the barrier window
      bar_wait(rootc, nbar, tid);
    }

    // ================= word attention: z[b,t] =================
    {
      const int ab = g >> 2, at0 = (g & 3) * 24;
      for (int half = 0; half < 2; ++half) {
        const int tb = at0 + half * 12;
        for (int idx = tid; idx < 12 * kH; idx += NTH) {
          int pp = idx >> 9, hh = idx & (kH - 1);
          attn_f[pp * 516 + hh] = hs_buf[(ab * kT + tb + pp) * kH + hh];
        }
        __syncthreads();
        const int aa = tid;  // NTH == kA
        float dacc[12];
#pragma unroll
        for (int p = 0; p < 12; ++p) dacc[p] = 0.f;
        const float4* __restrict__ wk = (const float4*)(wa_Wk + aa * kH);
        for (int k = 0; k < kH / 4; ++k) {
          float4 w = wk[k];
#pragma unroll
          for (int p = 0; p < 12; ++p)
            dacc[p] += dot4(w, *(const float4*)(&attn_f[p * 516 + k * 4]));
        }
        const float wv = wa_Wv[aa];
        const int lane = tid & 63, wid = tid >> 6;
#pragma unroll
        for (int p = 0; p < 12; ++p) {
          float v = wv * tanhf(dacc[p]);
          v += __shfl_down(v, 32); v += __shfl_down(v, 16); v += __shfl_down(v, 8);
          v += __shfl_down(v, 4);  v += __shfl_down(v, 2);  v += __shfl_down(v, 1);
          if (lane == 0) red_s[wid * 12 + p] = v;
        }
        __syncthreads();
        if (tid < 12) {
          float sum = 0.f;
#pragma unroll
          for (int w = 0; w < 8; ++w) sum += red_s[w * 12 + tid];
          z_buf[ab * kT + tb + tid] = sum;
        }
        __syncthreads();
      }
    }
    ++nbar; bar_arrive(grpc, rootc, nbar, g, tid); bar_wait(rootc, nbar, tid);

    // ================= softmax over T + ctx =================
    if (g < kB) {
      const int b = g;
      if (tid < kT) soft_s[tid] = z_buf[b * kT + tid];
      __syncthreads();
      float mx = -1e30f;
      for (int i = 0; i < kT; ++i) mx = fmaxf(mx, soft_s[i]);
      float den = 0.f;
      for (int i = 0; i < kT; ++i) den += expf(soft_s[i] - mx);
      __syncthreads();
      if (tid < kT) soft_s[tid] = expf(soft_s[tid] - mx) / den;
      __syncthreads();
      for (int h0 = tid; h0 < kH; h0 += NTH) {
        float acc = 0.f;
        for (int tt = 0; tt < kT; ++tt) acc += soft_s[tt] * hs_buf[(b * kT + tt) * kH + h0];
        ctx_ws[b * kH + h0] = acc;
      }
    }
    ++nbar; bar_arrive(grpc, rootc, nbar, g, tid); bar_wait(rootc, nbar, tid);

    // ================= sentence LSTM step =================
    {
      const float* shc = sh_buf + (s & 1) * kB * kH;
      float* shn = sh_buf + ((s + 1) & 1) * kB * kH;
      const int row = (jj >> 1) * kH + 2 * g + (jj & 1);
      float acc = s_bih[row] + s_bhh[row];
      const float4* __restrict__ wi = (const float4*)(s_Wih + row * kH);
      const float4* __restrict__ wh = (const float4*)(s_Whh + row * kH);
      const float4* __restrict__ x0 = (const float4*)(ctx_ws + bb * kH);
      const float4* __restrict__ h0 = (const float4*)(shc + bb * kH);
#pragma unroll 2
      for (int k = 0; k < kH / 4; ++k)
        acc += dot4(wi[k], x0[k]) + dot4(wh[k], h0[k]);
      g_s[jj][bb] = acc;
      __syncthreads();
      if (tid < 128) {
        const int p = tid & 1, b = tid >> 1;
        float gi = g_s[0 + p][b], gf = g_s[2 + p][b], gg = g_s[4 + p][b], go = g_s[6 + p][b];
        float c2 = sigmoidf(gf) * sc_s[p][b] + sigmoidf(gi) * tanhf(gg);
        float h2 = sigmoidf(go) * tanhf(c2);
        sc_s[p][b] = c2;
        const int col = 2 * g + p;
        shn[b * kH + col] = h2;
        sent_hs[(b * kS + s) * kH + col] = h2;
      }
    }
    ++nbar; bar_arrive(grpc, rootc, nbar, g, tid); bar_wait(rootc, nbar, tid);
  }

  // ================= final attention over S =================
  {
    const int pair0 = g * 6;  // 1536 (b,s) pairs / 256 WGs
    for (int idx = tid; idx < 6 * kH; idx += NTH) {
      int pp = idx >> 9, hh = idx & (kH - 1);
      attn_f[pp * 516 + hh] = sent_hs[(pair0 + pp) * kH + hh];
    }
    __syncthreads();
    const int aa = tid;
    float dacc[6];
#pragma unroll
    for (int p = 0; p < 6; ++p) dacc[p] = 0.f;
    const float4* __restrict__ wk = (const float4*)(sa_Wk + aa * kH);
    for (int k = 0; k < kH / 4; ++k) {
      float4 w = wk[k];
#pragma unroll
      for (int p = 0; p < 6; ++p)
        dacc[p] += dot4(w, *(const float4*)(&attn_f[p * 516 + k * 4]));
    }
    const float wv = sa_Wv[aa];
    const int lane = tid & 63, wid = tid >> 6;
#pragma unroll
    for (int p = 0; p < 6; ++p) {
      float v = wv * tanhf(dacc[p]);
      v += __shfl_down(v, 32); v += __shfl_down(v, 16); v += __shfl_down(v, 8);
      v += __shfl_down(v, 4);  v += __shfl_down(v, 2);  v += __shfl_down(v, 1);
      if (lane == 0) red_s[wid * 6 + p] = v;
    }
    __syncthreads();
    if (tid < 6) {
      float sum = 0.f;
#pragma unroll
      for (int w = 0; w < 8; ++w) sum += red_s[w * 6 + tid];
      z2_buf[pair0 + tid] = sum;
    }
  }
  ++nbar; bar_arrive(grpc, rootc, nbar, g, tid); bar_wait(rootc, nbar, tid);

  // ================= final softmax + outputs =================
  if (g < kB) {
    const int b = g;
    if (tid < kS) soft_s[tid] = z2_buf[b * kS + tid];
    __syncthreads();
    float mx = -1e30f;
    for (int i = 0; i < kS; ++i) mx = fmaxf(mx, soft_s[i]);
    float den = 0.f;
    for (int i = 0; i < kS; ++i) den += expf(soft_s[i] - mx);
    __syncthreads();
    if (tid < kS) {
      float al = expf(soft_s[tid] - mx) / den;
      soft_s[tid] = al;
      out[kB * kH + b * kS + tid] = al;  // alpha
    }
    __syncthreads();
    for (int h0 = tid; h0 < kH; h0 += NTH) {
      float acc = 0.f;
      for (int s2 = 0; s2 < kS; ++s2) acc += soft_s[s2] * sent_hs[(b * kS + s2) * kH + h0];
      out[b * kH + h0] = acc;  // context
    }
  }
}

extern "C" void kernel_launch(void* const* d_in, const int* in_sizes, int n_in,
                              void* d_out, int out_size, void* d_ws, size_t ws_size,
                              hipStream_t stream) {
  (void)in_sizes; (void)n_in; (void)out_size; (void)ws_size;
  const int* captions = (const int*)d_in[0];
  const int* masks = (const int*)d_in[1];
  const float* embed_W = (const float*)d_in[2];
  const float* w_Wih = (const float*)d_in[3];
  const float* w_Whh = (const float*)d_in[4];
  const float* w_bih = (const float*)d_in[5];
  const float* w_bhh = (const float*)d_in[6];
  const float* s_Wih = (const float*)d_in[7];
  const float* s_Whh = (const float*)d_in[8];
  const float* s_bih = (const float*)d_in[9];
  const float* s_bhh = (const float*)d_in[10];
  const float* wa_Wk = (const float*)d_in[11];
  const float* wa_Wv = (const float*)d_in[12];
  const float* sa_Wk = (const float*)d_in[13];
  const float* sa_Wv = (const float*)d_in[14];
  float* out = (float*)d_out;
  float* ws = (float*)d_ws;

  void* args[] = {&captions, &masks, &embed_W, &w_Wih, &w_Whh, &w_bih, &w_bhh,
                  &s_Wih, &s_Whh, &s_bih, &s_bhh, &wa_Wk, &wa_Wv, &sa_Wk, &sa_Wv,
                  &out, &ws};
  hipLaunchCooperativeKernel((void*)ha_kernel, dim3(NWG), dim3(NTH), args, 0, stream);
}